// Round 5
// baseline (296.476 us; speedup 1.0000x reference)
//
#include <hip/hip_runtime.h>
#include <math.h>

// DigitCaps dynamic routing. B=256, R=1152, C=10, O=16, I=8, 3 iters.
// R18: (1) all cross-block stores (part/vt/bij-init) become device-scope
// WRITE-THROUGH stores (global_store_* sc1) -> no dirty L2 lines -> the
// barrier needs NO wbl2 flush walk. Leader issues only the acquire inv,
// moved to leader-ARRIVAL time (overlaps the arrival window; safe since
// sc1 stores bypass L2 and laggard reads only refill immutable
// current-phase read regions). Barrier = arrive + poll + done. (2) regular
// graph-capturable launch instead of hipLaunchCooperativeKernel (R16/R17
// showed a constant ~82us dur-vs-kernel gap = coop launch overhead);
// co-residency is forced by geometry: 256 blocks / 256 CUs, 120KB LDS =
// 1 block/CU. Dataflow/numerics identical to R15-R17 (absmax 4.9e-4).

#define B_ 256
#define R_ 1152
#define N_ 160      // C*O
#define K_ 9216     // R*I
#define NS 128      // K splits of 72 (9 routes)
#define KB 72
#define LDK 104     // gemm LDS k-stride (bf16 elems)
#define LDB 136     // gtdot LDS b-stride (bf16 elems)

// workspace layout (byte offsets)
#define PART_ELEMS ((size_t)B_*NS*N_)          // 5,242,880 fp16 = 10.49 MB
#define BIJ_BOFF   (PART_ELEMS*2)
#define VT_BOFF    (BIJ_BOFF + (size_t)R_*10*4)
#define BAR_BOFF   (VT_BOFF + (size_t)N_*B_*2) // 7 ordinals x 256B
#define BAR_BYTES  2048

// static LDS pool (byte offsets)
#define ASG_OFF    0            // short[128*LDK]   26,624 B (persistent)
#define WF_OFF     26624        // float[160*72]    46,080 B (persistent)
#define SCR_OFF    72704        // scratch          47,520 B
//   gemm : Bs  short[160*LDK] 33,280 B
//   gtdot: Ast short[80*LDB]  21,760 B ; then LG float[72*165] 47,520 B
#define SMEM_BYTES 120224

typedef __attribute__((ext_vector_type(8))) short short8;
typedef __attribute__((ext_vector_type(4))) float f32x4;

static __device__ __forceinline__ short f2bf(float f) {   // RNE fp32->bf16
    unsigned u = __float_as_uint(f);
    unsigned r = (u + 0x7fffu + ((u >> 16) & 1u)) >> 16;
    return (short)r;
}

// Device-scope write-through stores: data goes past the (non-coherent) L2
// to the memory-side coherence point. vmcnt(0) (inside __syncthreads)
// then guarantees grid-wide visibility -- no wbl2 needed at barriers.
static __device__ __forceinline__ void st_u16_dev(void* p, unsigned v) {
    asm volatile("global_store_short %0, %1, off sc1"
                 :: "v"(p), "v"(v) : "memory");
}
static __device__ __forceinline__ void st_f32_dev(void* p, float v) {
    asm volatile("global_store_dword %0, %1, off sc1"
                 :: "v"(p), "v"(v) : "memory");
}

// Grid barrier v3. Per ordinal (64 dwords): [0..7] per-XCD leader claim,
// [8] arrive, [16] done. Counters zeroed by hipMemsetAsync each launch.
// Leader does the L2 inv AT ARRIVAL (overlapped with stragglers), then
// waits arrive==256 and bumps done. No release fence anywhere: all
// cross-block stores are sc1 write-through, drained by the entry
// __syncthreads' vmcnt(0).
static __device__ __forceinline__ void gbar(unsigned* __restrict__ bar,
                                            int id, int tid) {
    __syncthreads();   // per-wave s_waitcnt vmcnt(0): sc1 stores at MALL
    if (tid == 0) {
        unsigned* base = bar + id * 64;
        unsigned xcd;
        asm volatile("s_getreg_b32 %0, hwreg(HW_REG_XCC_ID)" : "=s"(xcd));
        xcd &= 7;
        bool lead = (__hip_atomic_fetch_add(base + xcd, 1u, __ATOMIC_RELAXED,
                                            __HIP_MEMORY_SCOPE_AGENT) == 0u);
        __hip_atomic_fetch_add(base + 8, 1u, __ATOMIC_RELAXED,
                               __HIP_MEMORY_SCOPE_AGENT);
        if (lead) {
            // one L2 inv per XCD, overlapped with the arrival window
            __builtin_amdgcn_fence(__ATOMIC_ACQUIRE, "agent");
            while (__hip_atomic_load(base + 8, __ATOMIC_RELAXED,
                                     __HIP_MEMORY_SCOPE_AGENT) < 256u)
                __builtin_amdgcn_s_sleep(1);
            __hip_atomic_fetch_add(base + 16, 1u, __ATOMIC_RELAXED,
                                   __HIP_MEMORY_SCOPE_AGENT);
        }
        while (__hip_atomic_load(base + 16, __ATOMIC_RELAXED,
                                 __HIP_MEMORY_SCOPE_AGENT) < 8u)
            __builtin_amdgcn_s_sleep(1);
    }
    __syncthreads();
    // compiler barrier + L1-level acquire (same as R17, 3x verified)
    __builtin_amdgcn_fence(__ATOMIC_ACQUIRE, "workgroup");
}

// ===========================================================================
// Fused persistent kernel (regular launch; 1 block/CU by LDS geometry)
// ===========================================================================
__global__ __launch_bounds__(256) void k_caps(const float* __restrict__ X,
                                              const float* __restrict__ W,
                                              _Float16* __restrict__ part,
                                              float* __restrict__ bij,
                                              short* __restrict__ vt,
                                              float* __restrict__ out,
                                              unsigned* __restrict__ bar) {
    __shared__ __align__(16) char smem[SMEM_BYTES];
    short* Asg = (short*)(smem + ASG_OFF);   // [b][k] bf16, persistent
    float* Wf  = (float*)(smem + WF_OFF);    // [n=c*16+o][k=rl*8+i] fp32, persistent
    short* Bs  = (short*)(smem + SCR_OFF);   // gemm: scaled W [n][k] bf16
    short* Ast = (short*)(smem + SCR_OFF);   // gtdot: X^T [k][b] bf16
    float* LG  = (float*)(smem + SCR_OFF);   // gtdot: G [72][165] fp32
    __shared__ float cs[90];
    __shared__ float red[40];
    __shared__ float dsm[10];

    const int tid = threadIdx.x;
    const int ks = blockIdx.x >> 1, bt = blockIdx.x & 1;  // == (kt, bh)
    const int b0 = bt * 128, k0 = ks * KB, r0 = ks * 9;

    // ---------------- P0: one-time persistent staging ----------------
    // X[128][72] -> bf16 Asg[b][k]
    #pragma unroll
    for (int j = 0; j < 9; ++j) {
        int q = j * 256 + tid;                     // < 2304
        int bb = q / 18, kf = q - bb * 18;
        float4 a = *(const float4*)(X + (size_t)(b0 + bb) * K_ + k0 + kf * 4);
        short4 h = make_short4(f2bf(a.x), f2bf(a.y), f2bf(a.z), f2bf(a.w));
        *(short4*)(&Asg[bb * LDK + kf * 4]) = h;
    }
    // zero Asg k-pad [72,96)
    #pragma unroll
    for (int j = 0; j < 3; ++j) {
        int q = j * 256 + tid;                     // < 768 = 128*6
        int bb = q / 6, ch = q - bb * 6;
        *(short4*)(&Asg[bb * LDK + 72 + ch * 4]) = make_short4(0, 0, 0, 0);
    }
    // W slice (9 routes) -> fp32 Wf[n][k]
    {
        const float* Wsl = W + (size_t)r0 * 1280;
        #pragma unroll
        for (int j = 0; j < 12; ++j) {
            int q = j * 256 + tid;
            if (q < 2880) {
                int rl = q / 320;
                int rem = q - rl * 320;
                int c = rem >> 5;
                int o = (rem & 31) >> 1;
                int i4 = rem & 1;
                float4 w = *(const float4*)(Wsl + (size_t)q * 4);
                *(float4*)(&Wf[(c * 16 + o) * 72 + rl * 8 + i4 * 4]) = w;
            }
        }
    }
    if (bt == 0 && tid < 90)
        st_f32_dev(&bij[r0 * 10 + tid], 0.0f);     // write-through init

    for (int it = 0; it < 3; ++it) {
        // ---------------- coupling coefficients cs[9][10] ----------------
        if (it == 0) {
            if (tid < 90) cs[tid] = 1.0f / 1152.0f;
        } else {
            float dcol[10];
            #pragma unroll
            for (int c = 0; c < 10; ++c) dcol[c] = 0.0f;
            for (int r = tid; r < R_; r += 256) {
                #pragma unroll
                for (int c = 0; c < 10; ++c) dcol[c] += __expf(bij[r * 10 + c]);
            }
            const int lane = tid & 63, wv = tid >> 6;
            #pragma unroll
            for (int c = 0; c < 10; ++c) {
                float s = dcol[c];
                #pragma unroll
                for (int off = 32; off > 0; off >>= 1) s += __shfl_down(s, off);
                if (lane == 0) red[wv * 10 + c] = s;
            }
            __syncthreads();
            if (tid < 10)
                dsm[tid] = red[tid] + red[10 + tid] + red[20 + tid] + red[30 + tid];
            __syncthreads();
            if (tid < 90) {
                int rr = tid / 10, cc = tid - rr * 10;
                cs[tid] = __expf(bij[(r0 + rr) * 10 + cc]) / dsm[cc];
            }
        }
        __syncthreads();   // cs ready (also orders P0 staging on iter 0)

        // ---------------- Bs = (cs ⊙ W) bf16, from LDS fp32 Wf ----------------
        #pragma unroll
        for (int j = 0; j < 12; ++j) {
            int q = j * 256 + tid;
            if (q < 2880) {                         // 160 rows * 18 float4
                int nn = q / 18, kk4 = q - nn * 18;
                float4 w = *(const float4*)(Wf + nn * 72 + kk4 * 4);
                int rl = kk4 >> 1;
                float sc = cs[rl * 10 + (nn >> 4)];
                short4 h = make_short4(f2bf(w.x * sc), f2bf(w.y * sc),
                                       f2bf(w.z * sc), f2bf(w.w * sc));
                *(short4*)(&Bs[nn * LDK + kk4 * 4]) = h;
            }
        }
        #pragma unroll
        for (int j = 0; j < 4; ++j) {
            int q = j * 256 + tid;
            if (q < 960) {                          // 160 rows * 6 pad chunks
                int nn = q / 6, ch = q - nn * 6;
                *(short4*)(&Bs[nn * LDK + 72 + ch * 4]) = make_short4(0, 0, 0, 0);
            }
        }
        __syncthreads();

        // ---------------- GEMM: part[b][ks][n] ----------------
        {
            const int wv = tid >> 6, lane = tid & 63;
            const int lrow = lane & 15, quad = lane >> 4;
            f32x4 acc[2][10];
            #pragma unroll
            for (int mi = 0; mi < 2; ++mi)
                #pragma unroll
                for (int nt = 0; nt < 10; ++nt) acc[mi][nt] = (f32x4)(0.0f);

            #pragma unroll
            for (int ksp = 0; ksp < 3; ++ksp) {
                const int ko = ksp * 32 + quad * 8;
                short8 afr[2], bfr[10];
                #pragma unroll
                for (int mi = 0; mi < 2; ++mi)
                    afr[mi] = *(const short8*)(&Asg[((wv * 2 + mi) * 16 + lrow) * LDK + ko]);
                #pragma unroll
                for (int nt = 0; nt < 10; ++nt)
                    bfr[nt] = *(const short8*)(&Bs[(nt * 16 + lrow) * LDK + ko]);
                #pragma unroll
                for (int mi = 0; mi < 2; ++mi)
                    #pragma unroll
                    for (int nt = 0; nt < 10; ++nt)
                        acc[mi][nt] = __builtin_amdgcn_mfma_f32_16x16x32_bf16(
                            afr[mi], bfr[nt], acc[mi][nt], 0, 0, 0);
            }
            // C store (fp16, write-through): row=(quad*4+reg), col=lrow
            #pragma unroll
            for (int mi = 0; mi < 2; ++mi) {
                int bbase = b0 + (wv * 2 + mi) * 16 + quad * 4;
                #pragma unroll
                for (int reg = 0; reg < 4; ++reg) {
                    _Float16* P = part + (size_t)(bbase + reg) * (NS * N_) + ks * N_ + lrow;
                    #pragma unroll
                    for (int nt = 0; nt < 10; ++nt) {
                        _Float16 h = (_Float16)acc[mi][nt][reg];
                        st_u16_dev((void*)(P + nt * 16),
                                   (unsigned)__builtin_bit_cast(unsigned short, h));
                    }
                }
            }
        }
        gbar(bar, it * 3 + 0, tid);

        // ---------------- reduce + squash (b = blockIdx.x) ----------------
        if (tid < 160) {
            const int b = blockIdx.x;
            const _Float16* p = part + (size_t)b * (NS * N_) + tid;
            float s = 0.0f;
            #pragma unroll 8
            for (int kk = 0; kk < NS; ++kk) s += (float)p[kk * N_];
            float v = s * fabsf(s) / (1.0f + s * s);   // elementwise squash
            if (it == 2) out[b * N_ + tid] = v;        // plain: end-of-kernel flush
            else st_u16_dev((void*)&vt[tid * 256 + b],
                            (unsigned)(unsigned short)f2bf(v));
        }
        if (it == 2) break;
        gbar(bar, it * 3 + 1, tid);

        // ---------- gtdot: G = X^T.V-half, then bij += W·G/B ----------
        // Ast[k][b] from persistent Asg[b][k] (LDS->LDS transpose)
        #pragma unroll
        for (int j = 0; j < 9; ++j) {
            int q = j * 256 + tid;                 // < 2304 = 128*18
            int bb = q / 18, kf = q - bb * 18;
            short4 a = *(const short4*)(&Asg[bb * LDK + kf * 4]);
            Ast[(kf * 4 + 0) * LDB + bb] = a.x;
            Ast[(kf * 4 + 1) * LDB + bb] = a.y;
            Ast[(kf * 4 + 2) * LDB + bb] = a.z;
            Ast[(kf * 4 + 3) * LDB + bb] = a.w;
        }
        __syncthreads();

        {
            const int wv = tid >> 6, lane = tid & 63;
            const int lrow = lane & 15, quad = lane >> 4;
            f32x4 acc[5][3];
            #pragma unroll
            for (int mt = 0; mt < 5; ++mt)
                #pragma unroll
                for (int sl = 0; sl < 3; ++sl) acc[mt][sl] = (f32x4)(0.0f);

            #pragma unroll
            for (int kb = 0; kb < 4; ++kb) {
                const int ko = kb * 32 + quad * 8;
                short8 af[5], bf[3];
                #pragma unroll
                for (int mt = 0; mt < 5; ++mt)
                    af[mt] = *(const short8*)(&Ast[(mt * 16 + lrow) * LDB + ko]);
                // V fragments direct from global vt[n][256b] (post-inv -> MALL)
                #pragma unroll
                for (int sl = 0; sl < 3; ++sl) {
                    int nt = wv + sl * 4;
                    if (nt < 10)
                        bf[sl] = *(const short8*)(vt + (nt * 16 + lrow) * 256 + b0 + ko);
                }
                #pragma unroll
                for (int mt = 0; mt < 5; ++mt)
                    #pragma unroll
                    for (int sl = 0; sl < 3; ++sl)
                        if (wv + sl * 4 < 10)
                            acc[mt][sl] = __builtin_amdgcn_mfma_f32_16x16x32_bf16(
                                af[mt], bf[sl], acc[mt][sl], 0, 0, 0);
            }
            __syncthreads();   // frag reads done; reuse scratch as LG

            #pragma unroll
            for (int mt = 0; mt < 5; ++mt) {
                #pragma unroll
                for (int sl = 0; sl < 3; ++sl) {
                    int nt = wv + sl * 4;
                    if (nt < 10) {
                        #pragma unroll
                        for (int reg = 0; reg < 4; ++reg) {
                            int m = mt * 16 + quad * 4 + reg;
                            if (m < 72)
                                LG[m * 165 + nt * 16 + lrow] = acc[mt][sl][reg];
                        }
                    }
                }
            }
        }
        __syncthreads();
        // per-route dot with W (fp32 from LDS), atomicAdd into bij
        if (tid < 90) {
            int rl = tid / 10, c = tid - rl * 10;
            int r = r0 + rl;
            const float* wbase = Wf + (c * 16) * 72 + rl * 8;
            float s = 0.0f;
            #pragma unroll
            for (int o = 0; o < 16; ++o) {
                const float* wp = wbase + o * 72;
                float4 wa = *(const float4*)(wp);
                float4 wb = *(const float4*)(wp + 4);
                const float* g = &LG[(rl * 8) * 165 + c * 16 + o];
                s += wa.x * g[0]       + wa.y * g[165]     + wa.z * g[2 * 165] +
                     wa.w * g[3 * 165] + wb.x * g[4 * 165] + wb.y * g[5 * 165] +
                     wb.z * g[6 * 165] + wb.w * g[7 * 165];
            }
            atomicAdd(&bij[r * 10 + c], s * (1.0f / B_));
        }
        gbar(bar, it * 3 + 2, tid);
    }
}

// ---------------------------------------------------------------------------
extern "C" void kernel_launch(void* const* d_in, const int* in_sizes, int n_in,
                              void* d_out, int out_size, void* d_ws, size_t ws_size,
                              hipStream_t stream) {
    const float* x = (const float*)d_in[0];   // (256, 1152, 8)
    const float* W = (const float*)d_in[1];   // (1152, 10, 16, 8)
    char* ws       = (char*)d_ws;
    _Float16* part = (_Float16*)ws;
    float* bij     = (float*)(ws + BIJ_BOFF);
    short* vt      = (short*)(ws + VT_BOFF);  // Vt[160][256] bf16
    unsigned* bar  = (unsigned*)(ws + BAR_BOFF);
    float* outf    = (float*)d_out;

    // re-arm the per-ordinal barrier counters on every launch/replay
    hipMemsetAsync((void*)bar, 0, BAR_BYTES, stream);

    // regular launch: 256 blocks x 256 thr, 120KB LDS => exactly 1 block/CU
    // on 256 CUs => all blocks co-resident (grid-barrier safe)
    k_caps<<<256, 256, 0, stream>>>(x, W, part, bij, vt, outf, bar);
}

// Round 7
// 165.665 us; speedup vs baseline: 1.7896x; 1.7896x over previous
//
#include <hip/hip_runtime.h>
#include <math.h>

// DigitCaps dynamic routing. B=256, R=1152, C=10, O=16, I=8, 3 iters.
// R20 = R19 with the compile fix: inline-asm "v" constraint can't take the
// HIP struct int4 -> use ext_vector_type(4) int (i32x4) for sc1 stores.
//  - part C-store: LDS bounce -> 16B dwordx4 sc1 (layout [b][ks][n] kept,
//    reduce verbatim). R18 showed scalar 2B sc1 stores are the regression.
//  - vt -> vt2[b][n]: reduce stores one coalesced 320B row; gtdot restages
//    to Vs[n][b] LDS via transpose (MFMA code unchanged).
//  - barrier: per-XCD claimer (first arriver) buffer_inv + vmcnt(0) BEFORE
//    arriving (done => all 8 L2 invs complete); arrival tree 32x8 by
//    blockIdx (max 32 same-line RMWs); no release fence (sc1 => no dirty
//    shared lines; R18 = correctness witness).
//  - regular (graph-capturable) launch; 256 blocks/256 CUs co-resident.

#define B_ 256
#define R_ 1152
#define N_ 160      // C*O
#define K_ 9216     // R*I
#define NS 128      // K splits of 72 (9 routes)
#define KB 72
#define LDK 104     // gemm LDS k-stride (bf16 elems)
#define LDB 136     // gtdot LDS b-stride (bf16 elems)

// workspace layout (byte offsets)
#define PART_ELEMS ((size_t)B_*NS*N_)          // 5,242,880 fp16 = 10.49 MB
#define BIJ_BOFF   (PART_ELEMS*2)
#define VT_BOFF    (BIJ_BOFF + (size_t)R_*10*4)
#define BAR_BOFF   (VT_BOFF + (size_t)N_*B_*2) // 7 ordinals x 3072B
#define BAR_BYTES  21504

// static LDS pool (byte offsets)
#define ASG_OFF    0            // short[128*LDK]   26,624 B (persistent)
#define WF_OFF     26624        // float[160*72]    46,080 B (persistent)
#define SCR_OFF    72704        // scratch          65,280 B
//   gemm : Bs short[160*LDK] 33,280 ; then CT fp16[128][160] 40,960
//   gtdot: Ast short[80*LDB] 21,760 + Vs short[160*LDB] 43,520 = 65,280
//          then LG float[72*165] 47,520 (aliases Ast+Vs after sync)
#define SMEM_BYTES 137984

typedef __attribute__((ext_vector_type(8))) short short8;
typedef __attribute__((ext_vector_type(4))) float f32x4;
typedef __attribute__((ext_vector_type(4))) int i32x4;   // asm-friendly 16B

static __device__ __forceinline__ short f2bf(float f) {   // RNE fp32->bf16
    unsigned u = __float_as_uint(f);
    unsigned r = (u + 0x7fffu + ((u >> 16) & 1u)) >> 16;
    return (short)r;
}

// coalesced device-scope write-through stores (16B and 4B)
static __device__ __forceinline__ void st_b128_dev(void* p, i32x4 v) {
    asm volatile("global_store_dwordx4 %0, %1, off sc1"
                 :: "v"(p), "v"(v) : "memory");
}
static __device__ __forceinline__ void st_f32_dev(void* p, float v) {
    asm volatile("global_store_dword %0, %1, off sc1"
                 :: "v"(p), "v"(v) : "memory");
}

// Grid barrier v4. Per ordinal (768 dwords = 3072B):
//   claim_x : dword  x*16   (x = XCD id, 8 lines)
//   group_g : dword 128+g*16 (g = blockIdx>>3, 32 lines, 8 arrivals each)
//   root    : dword 640
//   done    : dword 656
// All zeroed by hipMemsetAsync each launch (graph-captured).
// Claimer (first arriver per XCD) invalidates its L2 and WAITS for the inv
// before arriving -> done==1 implies every XCD's inv is complete.
static __device__ __forceinline__ void gbar(unsigned* __restrict__ bar,
                                            int id, int tid, int bidx) {
    __syncthreads();   // all waves' sc1 stores vmcnt-drained (at MALL)
    if (tid == 0) {
        unsigned* base = bar + id * 768;
        unsigned xcd;
        asm volatile("s_getreg_b32 %0, hwreg(HW_REG_XCC_ID)" : "=s"(xcd));
        xcd &= 7;
        if (__hip_atomic_fetch_add(base + xcd * 16, 1u, __ATOMIC_RELAXED,
                                   __HIP_MEMORY_SCOPE_AGENT) == 0u) {
            __builtin_amdgcn_fence(__ATOMIC_ACQUIRE, "agent");  // buffer_inv
            asm volatile("s_waitcnt vmcnt(0)" ::: "memory");    // inv done
        }
        unsigned g = (unsigned)bidx >> 3;
        if (__hip_atomic_fetch_add(base + 128 + g * 16, 1u, __ATOMIC_RELAXED,
                                   __HIP_MEMORY_SCOPE_AGENT) == 7u) {
            if (__hip_atomic_fetch_add(base + 640, 1u, __ATOMIC_RELAXED,
                                       __HIP_MEMORY_SCOPE_AGENT) == 31u)
                __hip_atomic_store(base + 656, 1u, __ATOMIC_RELAXED,
                                   __HIP_MEMORY_SCOPE_AGENT);
        }
        while (__hip_atomic_load(base + 656, __ATOMIC_RELAXED,
                                 __HIP_MEMORY_SCOPE_AGENT) == 0u)
            __builtin_amdgcn_s_sleep(1);
    }
    __syncthreads();
    __builtin_amdgcn_fence(__ATOMIC_ACQUIRE, "workgroup");  // L1 refresh
}

// ===========================================================================
// Fused persistent kernel (regular launch; 1 block/CU by LDS geometry)
// ===========================================================================
__global__ __launch_bounds__(256) void k_caps(const float* __restrict__ X,
                                              const float* __restrict__ W,
                                              _Float16* __restrict__ part,
                                              float* __restrict__ bij,
                                              short* __restrict__ vt2,
                                              float* __restrict__ out,
                                              unsigned* __restrict__ bar) {
    __shared__ __align__(16) char smem[SMEM_BYTES];
    short* Asg = (short*)(smem + ASG_OFF);   // [b][k] bf16, persistent
    float* Wf  = (float*)(smem + WF_OFF);    // [n][k] fp32, persistent
    short* Bs  = (short*)(smem + SCR_OFF);          // gemm: scaled W [n][k]
    _Float16* CT = (_Float16*)(smem + SCR_OFF);     // gemm: C-tile [128][160]
    short* Ast = (short*)(smem + SCR_OFF);          // gtdot: X^T [k][b]
    short* Vs  = (short*)(smem + SCR_OFF) + 80 * LDB; // gtdot: V [n][b]
    float* LG  = (float*)(smem + SCR_OFF);          // gtdot: G [72][165]
    __shared__ float cs[90];
    __shared__ float red[40];
    __shared__ float dsm[10];
    __shared__ __align__(16) short sv16[160];

    const int tid = threadIdx.x;
    const int ks = blockIdx.x >> 1, bt = blockIdx.x & 1;  // == (kt, bh)
    const int b0 = bt * 128, k0 = ks * KB, r0 = ks * 9;

    // ---------------- P0: one-time persistent staging ----------------
    #pragma unroll
    for (int j = 0; j < 9; ++j) {
        int q = j * 256 + tid;                     // < 2304
        int bb = q / 18, kf = q - bb * 18;
        float4 a = *(const float4*)(X + (size_t)(b0 + bb) * K_ + k0 + kf * 4);
        short4 h = make_short4(f2bf(a.x), f2bf(a.y), f2bf(a.z), f2bf(a.w));
        *(short4*)(&Asg[bb * LDK + kf * 4]) = h;
    }
    #pragma unroll
    for (int j = 0; j < 3; ++j) {
        int q = j * 256 + tid;                     // < 768 = 128*6
        int bb = q / 6, ch = q - bb * 6;
        *(short4*)(&Asg[bb * LDK + 72 + ch * 4]) = make_short4(0, 0, 0, 0);
    }
    {
        const float* Wsl = W + (size_t)r0 * 1280;
        #pragma unroll
        for (int j = 0; j < 12; ++j) {
            int q = j * 256 + tid;
            if (q < 2880) {
                int rl = q / 320;
                int rem = q - rl * 320;
                int c = rem >> 5;
                int o = (rem & 31) >> 1;
                int i4 = rem & 1;
                float4 w = *(const float4*)(Wsl + (size_t)q * 4);
                *(float4*)(&Wf[(c * 16 + o) * 72 + rl * 8 + i4 * 4]) = w;
            }
        }
    }
    if (bt == 0 && tid < 90)
        st_f32_dev(&bij[r0 * 10 + tid], 0.0f);     // write-through init

    for (int it = 0; it < 3; ++it) {
        // ---------------- coupling coefficients cs[9][10] ----------------
        if (it == 0) {
            if (tid < 90) cs[tid] = 1.0f / 1152.0f;
        } else {
            float dcol[10];
            #pragma unroll
            for (int c = 0; c < 10; ++c) dcol[c] = 0.0f;
            for (int r = tid; r < R_; r += 256) {
                #pragma unroll
                for (int c = 0; c < 10; ++c) dcol[c] += __expf(bij[r * 10 + c]);
            }
            const int lane = tid & 63, wv = tid >> 6;
            #pragma unroll
            for (int c = 0; c < 10; ++c) {
                float s = dcol[c];
                #pragma unroll
                for (int off = 32; off > 0; off >>= 1) s += __shfl_down(s, off);
                if (lane == 0) red[wv * 10 + c] = s;
            }
            __syncthreads();
            if (tid < 10)
                dsm[tid] = red[tid] + red[10 + tid] + red[20 + tid] + red[30 + tid];
            __syncthreads();
            if (tid < 90) {
                int rr = tid / 10, cc = tid - rr * 10;
                cs[tid] = __expf(bij[(r0 + rr) * 10 + cc]) / dsm[cc];
            }
        }
        __syncthreads();   // cs ready (also orders P0 staging on iter 0)

        // ---------------- Bs = (cs ⊙ W) bf16, from LDS fp32 Wf ----------------
        #pragma unroll
        for (int j = 0; j < 12; ++j) {
            int q = j * 256 + tid;
            if (q < 2880) {                         // 160 rows * 18 float4
                int nn = q / 18, kk4 = q - nn * 18;
                float4 w = *(const float4*)(Wf + nn * 72 + kk4 * 4);
                int rl = kk4 >> 1;
                float sc = cs[rl * 10 + (nn >> 4)];
                short4 h = make_short4(f2bf(w.x * sc), f2bf(w.y * sc),
                                       f2bf(w.z * sc), f2bf(w.w * sc));
                *(short4*)(&Bs[nn * LDK + kk4 * 4]) = h;
            }
        }
        #pragma unroll
        for (int j = 0; j < 4; ++j) {
            int q = j * 256 + tid;
            if (q < 960) {                          // 160 rows * 6 pad chunks
                int nn = q / 6, ch = q - nn * 6;
                *(short4*)(&Bs[nn * LDK + 72 + ch * 4]) = make_short4(0, 0, 0, 0);
            }
        }
        __syncthreads();

        // ---------------- GEMM: part[b][ks][n] ----------------
        {
            const int wv = tid >> 6, lane = tid & 63;
            const int lrow = lane & 15, quad = lane >> 4;
            f32x4 acc[2][10];
            #pragma unroll
            for (int mi = 0; mi < 2; ++mi)
                #pragma unroll
                for (int nt = 0; nt < 10; ++nt) acc[mi][nt] = (f32x4)(0.0f);

            #pragma unroll
            for (int ksp = 0; ksp < 3; ++ksp) {
                const int ko = ksp * 32 + quad * 8;
                short8 afr[2], bfr[10];
                #pragma unroll
                for (int mi = 0; mi < 2; ++mi)
                    afr[mi] = *(const short8*)(&Asg[((wv * 2 + mi) * 16 + lrow) * LDK + ko]);
                #pragma unroll
                for (int nt = 0; nt < 10; ++nt)
                    bfr[nt] = *(const short8*)(&Bs[(nt * 16 + lrow) * LDK + ko]);
                #pragma unroll
                for (int mi = 0; mi < 2; ++mi)
                    #pragma unroll
                    for (int nt = 0; nt < 10; ++nt)
                        acc[mi][nt] = __builtin_amdgcn_mfma_f32_16x16x32_bf16(
                            afr[mi], bfr[nt], acc[mi][nt], 0, 0, 0);
            }
            __syncthreads();   // all Bs frag reads done; CT may alias Bs

            // C -> LDS tile CT[b_local][n] (fp16)
            #pragma unroll
            for (int mi = 0; mi < 2; ++mi) {
                int rbase = (wv * 2 + mi) * 16 + quad * 4;
                #pragma unroll
                for (int reg = 0; reg < 4; ++reg) {
                    #pragma unroll
                    for (int nt = 0; nt < 10; ++nt)
                        CT[(rbase + reg) * 160 + nt * 16 + lrow] =
                            (_Float16)acc[mi][nt][reg];
                }
            }
            __syncthreads();

            // coalesced sc1 store: 2560 x 16B chunks (320B runs per b-row)
            #pragma unroll
            for (int j = 0; j < 10; ++j) {
                int c = j * 256 + tid;             // < 2560 = 128*20
                int bb = c / 20, h = c - bb * 20;
                i32x4 v = *(const i32x4*)(CT + bb * 160 + h * 8);
                _Float16* dst = part + ((size_t)(b0 + bb) * NS + ks) * N_ + h * 8;
                st_b128_dev((void*)dst, v);
            }
        }
        gbar(bar, it * 3 + 0, tid, blockIdx.x);

        // ---------------- reduce + squash (b = blockIdx.x) ----------------
        if (tid < 160) {
            const int b = blockIdx.x;
            const _Float16* p = part + (size_t)b * (NS * N_) + tid;
            float s = 0.0f;
            #pragma unroll 8
            for (int kk = 0; kk < NS; ++kk) s += (float)p[kk * N_];
            float v = s * fabsf(s) / (1.0f + s * s);   // elementwise squash
            if (it == 2) out[b * N_ + tid] = v;        // plain: kernel-end flush
            else         sv16[tid] = f2bf(v);
        }
        if (it == 2) break;
        __syncthreads();
        if (tid < 20) {                                // vt2[b][n]: 320B row
            i32x4 v = *(const i32x4*)(sv16 + tid * 8);
            st_b128_dev((void*)(vt2 + (size_t)blockIdx.x * N_ + tid * 8), v);
        }
        gbar(bar, it * 3 + 1, tid, blockIdx.x);

        // ---------- gtdot: G = X^T.V-half, then bij += W·G/B ----------
        // Ast[k][b] from persistent Asg[b][k] (LDS->LDS transpose)
        #pragma unroll
        for (int j = 0; j < 9; ++j) {
            int q = j * 256 + tid;                 // < 2304 = 128*18
            int bb = q / 18, kf = q - bb * 18;
            short4 a = *(const short4*)(&Asg[bb * LDK + kf * 4]);
            Ast[(kf * 4 + 0) * LDB + bb] = a.x;
            Ast[(kf * 4 + 1) * LDB + bb] = a.y;
            Ast[(kf * 4 + 2) * LDB + bb] = a.z;
            Ast[(kf * 4 + 3) * LDB + bb] = a.w;
        }
        // Vs[n][b] from vt2[b][n] (coalesced 8B reads, LDS transpose)
        #pragma unroll
        for (int j = 0; j < 20; ++j) {
            int c = j * 256 + tid;                 // < 5120 = 128*40
            int bb = c / 40, k4 = c - bb * 40, n0 = k4 * 4;
            short4 w = *(const short4*)(vt2 + (size_t)(b0 + bb) * N_ + n0);
            Vs[(n0 + 0) * LDB + bb] = w.x;
            Vs[(n0 + 1) * LDB + bb] = w.y;
            Vs[(n0 + 2) * LDB + bb] = w.z;
            Vs[(n0 + 3) * LDB + bb] = w.w;
        }
        __syncthreads();

        {
            const int wv = tid >> 6, lane = tid & 63;
            const int lrow = lane & 15, quad = lane >> 4;
            f32x4 acc[5][3];
            #pragma unroll
            for (int mt = 0; mt < 5; ++mt)
                #pragma unroll
                for (int sl = 0; sl < 3; ++sl) acc[mt][sl] = (f32x4)(0.0f);

            #pragma unroll
            for (int kb = 0; kb < 4; ++kb) {
                const int ko = kb * 32 + quad * 8;
                short8 af[5], bf[3];
                #pragma unroll
                for (int mt = 0; mt < 5; ++mt)
                    af[mt] = *(const short8*)(&Ast[(mt * 16 + lrow) * LDB + ko]);
                #pragma unroll
                for (int sl = 0; sl < 3; ++sl) {
                    int nt = wv + sl * 4;
                    if (nt < 10)
                        bf[sl] = *(const short8*)(&Vs[(nt * 16 + lrow) * LDB + ko]);
                }
                #pragma unroll
                for (int mt = 0; mt < 5; ++mt)
                    #pragma unroll
                    for (int sl = 0; sl < 3; ++sl)
                        if (wv + sl * 4 < 10)
                            acc[mt][sl] = __builtin_amdgcn_mfma_f32_16x16x32_bf16(
                                af[mt], bf[sl], acc[mt][sl], 0, 0, 0);
            }
            __syncthreads();   // frag reads done; reuse scratch as LG

            #pragma unroll
            for (int mt = 0; mt < 5; ++mt) {
                #pragma unroll
                for (int sl = 0; sl < 3; ++sl) {
                    int nt = wv + sl * 4;
                    if (nt < 10) {
                        #pragma unroll
                        for (int reg = 0; reg < 4; ++reg) {
                            int m = mt * 16 + quad * 4 + reg;
                            if (m < 72)
                                LG[m * 165 + nt * 16 + lrow] = acc[mt][sl][reg];
                        }
                    }
                }
            }
        }
        __syncthreads();
        // per-route dot with W (fp32 from LDS), atomicAdd into bij
        if (tid < 90) {
            int rl = tid / 10, c = tid - rl * 10;
            int r = r0 + rl;
            const float* wbase = Wf + (c * 16) * 72 + rl * 8;
            float s = 0.0f;
            #pragma unroll
            for (int o = 0; o < 16; ++o) {
                const float* wp = wbase + o * 72;
                float4 wa = *(const float4*)(wp);
                float4 wb = *(const float4*)(wp + 4);
                const float* g = &LG[(rl * 8) * 165 + c * 16 + o];
                s += wa.x * g[0]       + wa.y * g[165]     + wa.z * g[2 * 165] +
                     wa.w * g[3 * 165] + wb.x * g[4 * 165] + wb.y * g[5 * 165] +
                     wb.z * g[6 * 165] + wb.w * g[7 * 165];
            }
            atomicAdd(&bij[r * 10 + c], s * (1.0f / B_));
        }
        gbar(bar, it * 3 + 2, tid, blockIdx.x);
    }
}

// ---------------------------------------------------------------------------
extern "C" void kernel_launch(void* const* d_in, const int* in_sizes, int n_in,
                              void* d_out, int out_size, void* d_ws, size_t ws_size,
                              hipStream_t stream) {
    const float* x = (const float*)d_in[0];   // (256, 1152, 8)
    const float* W = (const float*)d_in[1];   // (1152, 10, 16, 8)
    char* ws       = (char*)d_ws;
    _Float16* part = (_Float16*)ws;
    float* bij     = (float*)(ws + BIJ_BOFF);
    short* vt2     = (short*)(ws + VT_BOFF);  // vt2[b=256][n=160] bf16
    unsigned* bar  = (unsigned*)(ws + BAR_BOFF);
    float* outf    = (float*)d_out;

    // re-arm all barrier counters on every launch/replay (graph node)
    hipMemsetAsync((void*)bar, 0, BAR_BYTES, stream);

    // regular launch: 256 blocks x 256 thr, 138KB LDS => 1 block/CU on
    // 256 CUs => all blocks co-resident (grid-barrier safe; R18 witnessed)
    k_caps<<<256, 256, 0, stream>>>(x, W, part, bij, vt2, outf, bar);
}

// Round 8
// 144.317 us; speedup vs baseline: 2.0543x; 1.1479x over previous
//
#include <hip/hip_runtime.h>
#include <math.h>

// DigitCaps dynamic routing. B=256, R=1152, C=10, O=16, I=8, 3 iters.
// R21: zero-cache-maintenance barrier. All cross-block STORES are sc1
// (device-scope, at coherence point — R18/R20 witnessed) and now all
// cross-block LOADS are __hip_atomic_load(RELAXED, AGENT) = global_load
// sc1 (device-scope, compiler-scheduled vmcnt/ILP). No cache can hold a
// stale line => barrier v5 = pure arrive-tree + poll, NO inv/wbl2/claim.
// Also: vt back to [n][256] (reduce stores 160 scalar 2B sc1; Vs staging
// becomes conflict-free short4 copies); Ast persistent (built once in P0);
// CT stride 168 (16B-aligned, halves CT write conflicts).
// Dataflow/numerics identical to R15-R20 (absmax 4.9e-4).

#define B_ 256
#define R_ 1152
#define N_ 160      // C*O
#define K_ 9216     // R*I
#define NS 128      // K splits of 72 (9 routes)
#define KB 72
#define LDK 104     // gemm LDS k-stride (bf16 elems)
#define LDB 136     // gtdot LDS b-stride (bf16 elems)
#define LDC 168     // CT LDS n-stride (fp16 elems; 336B rows, 16B aligned)

// workspace layout (byte offsets)
#define PART_ELEMS ((size_t)B_*NS*N_)          // 5,242,880 fp16 = 10.49 MB
#define BIJ_BOFF   (PART_ELEMS*2)
#define VT_BOFF    (BIJ_BOFF + (size_t)R_*10*4)
#define BAR_BOFF   (VT_BOFF + (size_t)N_*B_*2) // 7 ordinals x 800 dwords
#define BAR_BYTES  22400

// static LDS pool (byte offsets)
#define ASG_OFF    0            // short[128*LDK]   26,624 B (persistent)
#define AST_OFF    26624       // short[80*LDB]    21,760 B (persistent X^T)
#define WF_OFF     48384       // float[160*72]    46,080 B (persistent)
#define SCR_OFF    94464       // scratch          47,520 B
//   gemm : Bs short[160*LDK] 33,280 ; then CT fp16[128][LDC] 43,008
//   gtdot: Vs short[160*LDB] 43,520 ; then LG float[72*165] 47,520
#define SMEM_BYTES 141984

typedef __attribute__((ext_vector_type(8))) short short8;
typedef __attribute__((ext_vector_type(4))) float f32x4;
typedef __attribute__((ext_vector_type(4))) int i32x4;   // asm-friendly 16B

static __device__ __forceinline__ short f2bf(float f) {   // RNE fp32->bf16
    unsigned u = __float_as_uint(f);
    unsigned r = (u + 0x7fffu + ((u >> 16) & 1u)) >> 16;
    return (short)r;
}

// ---- device-scope (sc1) stores: data lands at the coherence point ----
static __device__ __forceinline__ void st_b128_dev(void* p, i32x4 v) {
    asm volatile("global_store_dwordx4 %0, %1, off sc1"
                 :: "v"(p), "v"(v) : "memory");
}
static __device__ __forceinline__ void st_u16_dev(void* p, unsigned v) {
    asm volatile("global_store_short %0, %1, off sc1"
                 :: "v"(p), "v"(v) : "memory");
}
static __device__ __forceinline__ void st_f32_dev(void* p, float v) {
    asm volatile("global_store_dword %0, %1, off sc1"
                 :: "v"(p), "v"(v) : "memory");
}

// ---- device-scope loads (sc1; bypass non-coherent L1/L2), compiler-
// scheduled so vmcnt pipelining / ILP is preserved ----
static __device__ __forceinline__ float ldf_dev(const float* p) {
    unsigned u = __hip_atomic_load((const unsigned*)p, __ATOMIC_RELAXED,
                                   __HIP_MEMORY_SCOPE_AGENT);
    return __builtin_bit_cast(float, u);
}
static __device__ __forceinline__ float ldh_dev(const _Float16* p) {
    unsigned short u = __hip_atomic_load((const unsigned short*)p,
                                         __ATOMIC_RELAXED,
                                         __HIP_MEMORY_SCOPE_AGENT);
    return (float)__builtin_bit_cast(_Float16, u);
}
static __device__ __forceinline__ unsigned long long ld64_dev(const void* p) {
    return __hip_atomic_load((const unsigned long long*)p, __ATOMIC_RELAXED,
                             __HIP_MEMORY_SCOPE_AGENT);
}

// Grid barrier v5: PURE counter sync (no cache maintenance — sc1 on both
// sides makes it unnecessary). 3-level arrive tree, every counter on its
// own 64B line: group g=bid>>3 (32x8) -> mid m=g>>2 (8x4) -> root (8) ->
// done[xcd] x8 flags (32 pollers each). Zeroed by hipMemsetAsync per
// launch. Entry __syncthreads drains each wave's sc1 stores (vmcnt(0))
// before tid0 arrives => done implies all blocks' data at coherence point.
static __device__ __forceinline__ void gbar(unsigned* __restrict__ bar,
                                            int id, int tid, int bidx) {
    __syncthreads();
    if (tid == 0) {
        unsigned* base = bar + id * 800;
        unsigned xcd;
        asm volatile("s_getreg_b32 %0, hwreg(HW_REG_XCC_ID)" : "=s"(xcd));
        xcd &= 7;
        unsigned g = (unsigned)bidx >> 3;
        if (__hip_atomic_fetch_add(base + g * 16, 1u, __ATOMIC_RELAXED,
                                   __HIP_MEMORY_SCOPE_AGENT) == 7u) {
            unsigned m = g >> 2;
            if (__hip_atomic_fetch_add(base + 512 + m * 16, 1u,
                                       __ATOMIC_RELAXED,
                                       __HIP_MEMORY_SCOPE_AGENT) == 3u) {
                if (__hip_atomic_fetch_add(base + 640, 1u, __ATOMIC_RELAXED,
                                           __HIP_MEMORY_SCOPE_AGENT) == 7u) {
                    #pragma unroll
                    for (int x = 0; x < 8; ++x)
                        __hip_atomic_store(base + 656 + x * 16, 1u,
                                           __ATOMIC_RELAXED,
                                           __HIP_MEMORY_SCOPE_AGENT);
                }
            }
        }
        while (__hip_atomic_load(base + 656 + xcd * 16, __ATOMIC_RELAXED,
                                 __HIP_MEMORY_SCOPE_AGENT) == 0u)
            __builtin_amdgcn_s_sleep(2);
    }
    __syncthreads();
    __builtin_amdgcn_fence(__ATOMIC_ACQUIRE, "workgroup");  // cheap: waitcnt
}

// ===========================================================================
// Fused persistent kernel (regular launch; 1 block/CU by LDS geometry)
// ===========================================================================
__global__ __launch_bounds__(256) void k_caps(const float* __restrict__ X,
                                              const float* __restrict__ W,
                                              _Float16* __restrict__ part,
                                              float* __restrict__ bij,
                                              short* __restrict__ vt,
                                              float* __restrict__ out,
                                              unsigned* __restrict__ bar) {
    __shared__ __align__(16) char smem[SMEM_BYTES];
    short* Asg = (short*)(smem + ASG_OFF);   // [b][k] bf16, persistent
    short* Ast = (short*)(smem + AST_OFF);   // [k][b] bf16, persistent X^T
    float* Wf  = (float*)(smem + WF_OFF);    // [n][k] fp32, persistent
    short* Bs  = (short*)(smem + SCR_OFF);          // gemm: scaled W [n][k]
    _Float16* CT = (_Float16*)(smem + SCR_OFF);     // gemm: C-tile [128][LDC]
    short* Vs  = (short*)(smem + SCR_OFF);          // gtdot: V [n][b]
    float* LG  = (float*)(smem + SCR_OFF);          // gtdot: G [72][165]
    __shared__ float cs[90];
    __shared__ float red[40];
    __shared__ float dsm[10];

    const int tid = threadIdx.x;
    const int ks = blockIdx.x >> 1, bt = blockIdx.x & 1;  // == (kt, bh)
    const int b0 = bt * 128, k0 = ks * KB, r0 = ks * 9;

    // ---------------- P0: one-time persistent staging ----------------
    // X[128][72] -> bf16 Asg[b][k] AND Ast[k][b] (transpose built once)
    #pragma unroll
    for (int j = 0; j < 9; ++j) {
        int q = j * 256 + tid;                     // < 2304
        int bb = q / 18, kf = q - bb * 18;
        float4 a = *(const float4*)(X + (size_t)(b0 + bb) * K_ + k0 + kf * 4);
        short4 h = make_short4(f2bf(a.x), f2bf(a.y), f2bf(a.z), f2bf(a.w));
        *(short4*)(&Asg[bb * LDK + kf * 4]) = h;
        Ast[(kf * 4 + 0) * LDB + bb] = h.x;
        Ast[(kf * 4 + 1) * LDB + bb] = h.y;
        Ast[(kf * 4 + 2) * LDB + bb] = h.z;
        Ast[(kf * 4 + 3) * LDB + bb] = h.w;
    }
    #pragma unroll
    for (int j = 0; j < 3; ++j) {
        int q = j * 256 + tid;                     // < 768 = 128*6
        int bb = q / 6, ch = q - bb * 6;
        *(short4*)(&Asg[bb * LDK + 72 + ch * 4]) = make_short4(0, 0, 0, 0);
    }
    {
        const float* Wsl = W + (size_t)r0 * 1280;
        #pragma unroll
        for (int j = 0; j < 12; ++j) {
            int q = j * 256 + tid;
            if (q < 2880) {
                int rl = q / 320;
                int rem = q - rl * 320;
                int c = rem >> 5;
                int o = (rem & 31) >> 1;
                int i4 = rem & 1;
                float4 w = *(const float4*)(Wsl + (size_t)q * 4);
                *(float4*)(&Wf[(c * 16 + o) * 72 + rl * 8 + i4 * 4]) = w;
            }
        }
    }
    if (bt == 0 && tid < 90)
        st_f32_dev(&bij[r0 * 10 + tid], 0.0f);     // device-scope init

    for (int it = 0; it < 3; ++it) {
        // ---------------- coupling coefficients cs[9][10] ----------------
        if (it == 0) {
            if (tid < 90) cs[tid] = 1.0f / 1152.0f;
        } else {
            float dcol[10];
            #pragma unroll
            for (int c = 0; c < 10; ++c) dcol[c] = 0.0f;
            for (int r = tid; r < R_; r += 256) {
                const float* row = bij + r * 10;
                #pragma unroll
                for (int k = 0; k < 5; ++k) {
                    unsigned long long u = ld64_dev(row + k * 2);
                    float2 f = __builtin_bit_cast(float2, u);
                    dcol[k * 2]     += __expf(f.x);
                    dcol[k * 2 + 1] += __expf(f.y);
                }
            }
            const int lane = tid & 63, wv = tid >> 6;
            #pragma unroll
            for (int c = 0; c < 10; ++c) {
                float s = dcol[c];
                #pragma unroll
                for (int off = 32; off > 0; off >>= 1) s += __shfl_down(s, off);
                if (lane == 0) red[wv * 10 + c] = s;
            }
            __syncthreads();
            if (tid < 10)
                dsm[tid] = red[tid] + red[10 + tid] + red[20 + tid] + red[30 + tid];
            __syncthreads();
            if (tid < 90) {
                int rr = tid / 10, cc = tid - rr * 10;
                cs[tid] = __expf(ldf_dev(&bij[(r0 + rr) * 10 + cc])) / dsm[cc];
            }
        }
        __syncthreads();   // cs ready (also orders P0 staging on iter 0)

        // ---------------- Bs = (cs ⊙ W) bf16, from LDS fp32 Wf ----------------
        #pragma unroll
        for (int j = 0; j < 12; ++j) {
            int q = j * 256 + tid;
            if (q < 2880) {                         // 160 rows * 18 float4
                int nn = q / 18, kk4 = q - nn * 18;
                float4 w = *(const float4*)(Wf + nn * 72 + kk4 * 4);
                int rl = kk4 >> 1;
                float sc = cs[rl * 10 + (nn >> 4)];
                short4 h = make_short4(f2bf(w.x * sc), f2bf(w.y * sc),
                                       f2bf(w.z * sc), f2bf(w.w * sc));
                *(short4*)(&Bs[nn * LDK + kk4 * 4]) = h;
            }
        }
        #pragma unroll
        for (int j = 0; j < 4; ++j) {
            int q = j * 256 + tid;
            if (q < 960) {                          // 160 rows * 6 pad chunks
                int nn = q / 6, ch = q - nn * 6;
                *(short4*)(&Bs[nn * LDK + 72 + ch * 4]) = make_short4(0, 0, 0, 0);
            }
        }
        __syncthreads();

        // ---------------- GEMM: part[b][ks][n] ----------------
        {
            const int wv = tid >> 6, lane = tid & 63;
            const int lrow = lane & 15, quad = lane >> 4;
            f32x4 acc[2][10];
            #pragma unroll
            for (int mi = 0; mi < 2; ++mi)
                #pragma unroll
                for (int nt = 0; nt < 10; ++nt) acc[mi][nt] = (f32x4)(0.0f);

            #pragma unroll
            for (int ksp = 0; ksp < 3; ++ksp) {
                const int ko = ksp * 32 + quad * 8;
                short8 afr[2], bfr[10];
                #pragma unroll
                for (int mi = 0; mi < 2; ++mi)
                    afr[mi] = *(const short8*)(&Asg[((wv * 2 + mi) * 16 + lrow) * LDK + ko]);
                #pragma unroll
                for (int nt = 0; nt < 10; ++nt)
                    bfr[nt] = *(const short8*)(&Bs[(nt * 16 + lrow) * LDK + ko]);
                #pragma unroll
                for (int mi = 0; mi < 2; ++mi)
                    #pragma unroll
                    for (int nt = 0; nt < 10; ++nt)
                        acc[mi][nt] = __builtin_amdgcn_mfma_f32_16x16x32_bf16(
                            afr[mi], bfr[nt], acc[mi][nt], 0, 0, 0);
            }
            __syncthreads();   // all Bs frag reads done; CT may alias Bs

            // C -> LDS tile CT[b_local][n] (fp16, stride LDC=168)
            #pragma unroll
            for (int mi = 0; mi < 2; ++mi) {
                int rbase = (wv * 2 + mi) * 16 + quad * 4;
                #pragma unroll
                for (int reg = 0; reg < 4; ++reg) {
                    #pragma unroll
                    for (int nt = 0; nt < 10; ++nt)
                        CT[(rbase + reg) * LDC + nt * 16 + lrow] =
                            (_Float16)acc[mi][nt][reg];
                }
            }
            __syncthreads();

            // coalesced sc1 store: 2560 x 16B chunks (320B runs per b-row)
            #pragma unroll
            for (int j = 0; j < 10; ++j) {
                int c = j * 256 + tid;             // < 2560 = 128*20
                int bb = c / 20, h = c - bb * 20;
                i32x4 v = *(const i32x4*)(CT + bb * LDC + h * 8);
                _Float16* dst = part + ((size_t)(b0 + bb) * NS + ks) * N_ + h * 8;
                st_b128_dev((void*)dst, v);
            }
        }
        gbar(bar, it * 3 + 0, tid, blockIdx.x);

        // ---------------- reduce + squash (b = blockIdx.x) ----------------
        if (tid < 160) {
            const int b = blockIdx.x;
            const _Float16* p = part + (size_t)b * (NS * N_) + tid;
            float s = 0.0f;
            #pragma unroll 8
            for (int kk = 0; kk < NS; ++kk) s += ldh_dev(p + kk * N_);
            float v = s * fabsf(s) / (1.0f + s * s);   // elementwise squash
            if (it == 2) out[b * N_ + tid] = v;        // plain: kernel-end flush
            else st_u16_dev((void*)&vt[tid * 256 + b],
                            (unsigned)(unsigned short)f2bf(v));
        }
        if (it == 2) break;
        gbar(bar, it * 3 + 1, tid, blockIdx.x);

        // ---------- gtdot: G = X^T.V-half, then bij += W·G/B ----------
        // Vs[n][b] from vt[n][256] (8B agent loads, conflict-free copies)
        #pragma unroll
        for (int j = 0; j < 20; ++j) {
            int c = j * 256 + tid;                 // < 5120 = 160*32
            int n = c >> 5, s4 = c & 31;
            unsigned long long u = ld64_dev(vt + n * 256 + b0 + s4 * 4);
            *(short4*)(&Vs[n * LDB + s4 * 4]) = __builtin_bit_cast(short4, u);
        }
        __syncthreads();

        {
            const int wv = tid >> 6, lane = tid & 63;
            const int lrow = lane & 15, quad = lane >> 4;
            f32x4 acc[5][3];
            #pragma unroll
            for (int mt = 0; mt < 5; ++mt)
                #pragma unroll
                for (int sl = 0; sl < 3; ++sl) acc[mt][sl] = (f32x4)(0.0f);

            #pragma unroll
            for (int kb = 0; kb < 4; ++kb) {
                const int ko = kb * 32 + quad * 8;
                short8 af[5], bf[3];
                #pragma unroll
                for (int mt = 0; mt < 5; ++mt)
                    af[mt] = *(const short8*)(&Ast[(mt * 16 + lrow) * LDB + ko]);
                #pragma unroll
                for (int sl = 0; sl < 3; ++sl) {
                    int nt = wv + sl * 4;
                    if (nt < 10)
                        bf[sl] = *(const short8*)(&Vs[(nt * 16 + lrow) * LDB + ko]);
                }
                #pragma unroll
                for (int mt = 0; mt < 5; ++mt)
                    #pragma unroll
                    for (int sl = 0; sl < 3; ++sl)
                        if (wv + sl * 4 < 10)
                            acc[mt][sl] = __builtin_amdgcn_mfma_f32_16x16x32_bf16(
                                af[mt], bf[sl], acc[mt][sl], 0, 0, 0);
            }
            __syncthreads();   // Vs frag reads done; reuse scratch as LG

            #pragma unroll
            for (int mt = 0; mt < 5; ++mt) {
                #pragma unroll
                for (int sl = 0; sl < 3; ++sl) {
                    int nt = wv + sl * 4;
                    if (nt < 10) {
                        #pragma unroll
                        for (int reg = 0; reg < 4; ++reg) {
                            int m = mt * 16 + quad * 4 + reg;
                            if (m < 72)
                                LG[m * 165 + nt * 16 + lrow] = acc[mt][sl][reg];
                        }
                    }
                }
            }
        }
        __syncthreads();
        // per-route dot with W (fp32 from LDS), atomicAdd into bij
        if (tid < 90) {
            int rl = tid / 10, c = tid - rl * 10;
            int r = r0 + rl;
            const float* wbase = Wf + (c * 16) * 72 + rl * 8;
            float s = 0.0f;
            #pragma unroll
            for (int o = 0; o < 16; ++o) {
                const float* wp = wbase + o * 72;
                float4 wa = *(const float4*)(wp);
                float4 wb = *(const float4*)(wp + 4);
                const float* g = &LG[(rl * 8) * 165 + c * 16 + o];
                s += wa.x * g[0]       + wa.y * g[165]     + wa.z * g[2 * 165] +
                     wa.w * g[3 * 165] + wb.x * g[4 * 165] + wb.y * g[5 * 165] +
                     wb.z * g[6 * 165] + wb.w * g[7 * 165];
            }
            atomicAdd(&bij[r * 10 + c], s * (1.0f / B_));
        }
        gbar(bar, it * 3 + 2, tid, blockIdx.x);
    }
}

// ---------------------------------------------------------------------------
extern "C" void kernel_launch(void* const* d_in, const int* in_sizes, int n_in,
                              void* d_out, int out_size, void* d_ws, size_t ws_size,
                              hipStream_t stream) {
    const float* x = (const float*)d_in[0];   // (256, 1152, 8)
    const float* W = (const float*)d_in[1];   // (1152, 10, 16, 8)
    char* ws       = (char*)d_ws;
    _Float16* part = (_Float16*)ws;
    float* bij     = (float*)(ws + BIJ_BOFF);
    short* vt      = (short*)(ws + VT_BOFF);  // vt[n=160][b=256] bf16
    unsigned* bar  = (unsigned*)(ws + BAR_BOFF);
    float* outf    = (float*)d_out;

    // re-arm all barrier counters on every launch/replay (graph node)
    hipMemsetAsync((void*)bar, 0, BAR_BYTES, stream);

    // regular launch: 256 blocks x 256 thr, 142KB LDS => 1 block/CU on
    // 256 CUs => all blocks co-resident (grid-barrier safe; R18/R20
    // witnessed)
    k_caps<<<256, 256, 0, stream>>>(x, W, part, bij, vt, outf, bar);
}